// Round 17
// baseline (270.031 us; speedup 1.0000x reference)
//
#include <hip/hip_runtime.h>

typedef __attribute__((ext_vector_type(8))) short short8;
typedef __attribute__((ext_vector_type(4))) float f32x4;

#define S_LEN 2048
#define DH 64

__device__ __forceinline__ unsigned short f2bf(float x) {
  unsigned u = __builtin_bit_cast(unsigned, x);
  u += 0x7fffu + ((u >> 16) & 1u);
  return (unsigned short)(u >> 16);
}

// ---- detect whether mask was passed as uint8 (stride 1) or int32 (stride 4)
__global__ void detect_stride_k(const unsigned char* __restrict__ m, int* flag) {
  __shared__ int any;
  if (threadIdx.x == 0) any = 0;
  __syncthreads();
  int acc = 0;
  for (int i = threadIdx.x; i < 4096; i += 256)
    if (i & 3) acc |= m[i];
  if (acc) atomicOr(&any, 1);
  __syncthreads();
  if (threadIdx.x == 0) *flag = any ? 1 : 4;
}

// ---- merged prep: conv K->bf16 | transpose V->bf16 | pack mask bits ----
__global__ void prep_kernel(const float* __restrict__ k,
                            const float* __restrict__ v,
                            const unsigned char* __restrict__ m,
                            const int* __restrict__ flagp,
                            char* __restrict__ kbf,
                            char* __restrict__ vtbf,
                            unsigned* __restrict__ bits) {
  int bid = blockIdx.x;
  if (bid < 2048) {
    int idx = bid * 256 + threadIdx.x;
    const float4* s = (const float4*)k + (size_t)idx * 2;
    float4 a = s[0], b = s[1];
    int4 o;
    o.x = (int)f2bf(a.x) | ((int)f2bf(a.y) << 16);
    o.y = (int)f2bf(a.z) | ((int)f2bf(a.w) << 16);
    o.z = (int)f2bf(b.x) | ((int)f2bf(b.y) << 16);
    o.w = (int)f2bf(b.z) | ((int)f2bf(b.w) << 16);
    ((int4*)kbf)[idx] = o;
  } else if (bid < 6144) {
    int gt = (bid - 2048) * 256 + threadIdx.x;
    int wid = gt >> 6;
    int lane = gt & 63;
    int bh = wid >> 9;
    int rem = wid & 511;
    int d0 = (rem >> 5) * 4;
    int t = (rem & 31) * 64 + lane;
    float4 val = *(const float4*)(v + ((size_t)bh * S_LEN + t) * DH + d0);
    unsigned short* o = (unsigned short*)vtbf;
    size_t base = ((size_t)bh * DH + d0) * S_LEN + t;
    o[base]             = f2bf(val.x);
    o[base + S_LEN]     = f2bf(val.y);
    o[base + 2 * S_LEN] = f2bf(val.z);
    o[base + 3 * S_LEN] = f2bf(val.w);
  } else {
    int idx = (bid - 6144) * 256 + threadIdx.x;
    unsigned wword = 0;
    if (*flagp == 1) {
      const uint4* p = (const uint4*)(m + (size_t)idx * 32);
      uint4 a = p[0], bq = p[1];
      unsigned arr[8] = {a.x, a.y, a.z, a.w, bq.x, bq.y, bq.z, bq.w};
#pragma unroll
      for (int d = 0; d < 8; ++d)
#pragma unroll
        for (int j = 0; j < 4; ++j)
          wword |= (((arr[d] >> (8 * j)) & 255u) != 0u ? 1u : 0u) << (d * 4 + j);
    } else {
      const uint4* p = (const uint4*)m + (size_t)idx * 8;
#pragma unroll
      for (int d = 0; d < 8; ++d) {
        uint4 vv = p[d];
        wword |= (vv.x ? 1u : 0u) << (d * 4);
        wword |= (vv.y ? 1u : 0u) << (d * 4 + 1);
        wword |= (vv.z ? 1u : 0u) << (d * 4 + 2);
        wword |= (vv.w ? 1u : 0u) << (d * 4 + 3);
      }
    }
    bits[idx] = wword;
  }
}

// ======= FUSED: 4(qw)x2(tw) wave grid, 32q x 64t wave-tiles ================
// 512 blocks x 8 waves; LDS/wave/tile: K 8K + V 8K + P 8K (was 40K).
__global__ __launch_bounds__(512, 4)
void attn_fused(const float* __restrict__ qsrc,
                const unsigned* __restrict__ mbits,
                const char* __restrict__ kbf,
                const char* __restrict__ vtbf,
                float* __restrict__ out) {
  // 80 KiB: kbuf[2][16K] | vbuf[2][16K] | pbuf[8 waves][2K]
  __shared__ __align__(16) char smem[81920];

  const int tid = threadIdx.x;
  const int lane = tid & 63;
  const int w = tid >> 6;              // 0..7
  const int qw = w >> 1;               // 0..3
  const int tw = w & 1;                // 0..1
  const int l15 = lane & 15;
  const int g = lane >> 4;
  const int sw = (l15 & 7) << 4;

  // XCD-aware swizzle: 512 blocks -> 4 consecutive bh per XCD
  int raw = blockIdx.x;
  int swz = (raw & 7) * 64 + (raw >> 3);
  const int bh = swz >> 4;
  const int qblk = swz & 15;
  const int b = bh >> 4;
  const int q0 = qblk * 128 + qw * 32;   // this wave's 32 q-rows

  const char* ksrc_bh = kbf + (size_t)bh * (S_LEN * DH * 2);
  const char* vsrc_bh = vtbf + (size_t)bh * (DH * S_LEN * 2);
  char* pb = smem + 65536 + w * 2048;    // 16 rows x 128 B, wave-private
  float* sums = (float*)(smem + 65536);  // 128 floats (reused post-pass A)
  float* invl = (float*)(smem + 66048);  // 128 floats

  const unsigned* mb_b = mbits + (size_t)b * (S_LEN * (S_LEN / 32));
  const unsigned* mrow0 = mb_b + (size_t)(q0 + l15) * 64;
  const unsigned* mrow1 = mb_b + (size_t)(q0 + 16 + l15) * 64;

  auto stageK = [&](int buf, int t0) {
    char* dst = smem + buf * 16384;
#pragma unroll
    for (int it = 0; it < 2; ++it) {
      int o = (w * 2 + it) * 1024 + lane * 16;
      int r = o >> 7;
      int inner = o & 127;
      const char* gp = ksrc_bh + (size_t)t0 * 128 + r * 128 + (inner ^ ((r & 7) << 4));
      __builtin_amdgcn_global_load_lds((const unsigned*)gp,
                                       (unsigned*)(dst + (w * 2 + it) * 1024), 16, 0, 0);
    }
  };
  auto stageV = [&](int buf, int t0) {
    char* dst = smem + 32768 + buf * 16384;
#pragma unroll
    for (int it = 0; it < 2; ++it) {
      int o = (w * 2 + it) * 1024 + lane * 16;
      int r = o >> 8;
      int inner = o & 255;
      const char* gp = vsrc_bh + (size_t)t0 * 2 + (size_t)r * (S_LEN * 2) +
                       (inner ^ ((r & 7) << 4));
      __builtin_amdgcn_global_load_lds((const unsigned*)gp,
                                       (unsigned*)(dst + (w * 2 + it) * 1024), 16, 0, 0);
    }
  };

  // Q fragments: qf[qs][kc], lane holds Q[q0+16qs+l15][32kc+8g+j]
  short8 qf[2][2];
#pragma unroll
  for (int qs = 0; qs < 2; ++qs)
#pragma unroll
    for (int kc = 0; kc < 2; ++kc) {
      const float* qp = qsrc + ((size_t)bh * S_LEN + q0 + 16 * qs + l15) * DH + 32 * kc + 8 * g;
      float4 x = *(const float4*)qp;
      float4 y = *(const float4*)(qp + 4);
      short8 f;
      f[0] = (short)f2bf(x.x); f[1] = (short)f2bf(x.y);
      f[2] = (short)f2bf(x.z); f[3] = (short)f2bf(x.w);
      f[4] = (short)f2bf(y.x); f[5] = (short)f2bf(y.y);
      f[6] = (short)f2bf(y.z); f[7] = (short)f2bf(y.w);
      qf[qs][kc] = f;
    }

  f32x4 acc[4][2];
#pragma unroll
  for (int i = 0; i < 4; ++i)
#pragma unroll
    for (int j = 0; j < 2; ++j) acc[i][j] = (f32x4){0.f, 0.f, 0.f, 0.f};
  float lp0 = 0.f, lp1 = 0.f;

  // ---------------- PASS A (pipelined, staged; t-partial acc) --------------
  stageK(0, 0);
  stageV(0, 0);
  uint2 mw0 = *(const uint2*)(mrow0 + 2 * tw);
  uint2 mw1 = *(const uint2*)(mrow1 + 2 * tw);
  __syncthreads();
  int cur = 0;

  for (int t0 = 0; t0 < S_LEN; t0 += 128) {
    uint2 mwn0, mwn1;
    if (t0 + 128 < S_LEN) {
      stageK(cur ^ 1, t0 + 128);
      stageV(cur ^ 1, t0 + 128);
      mwn0 = *(const uint2*)(mrow0 + (t0 + 128) / 32 + 2 * tw);
      mwn1 = *(const uint2*)(mrow1 + (t0 + 128) / 32 + 2 * tw);
    }
    const char* kbuf = smem + cur * 16384;
    const char* vbuf = smem + 32768 + cur * 16384;

    // GEMM1 (swapped): own 64-t half; sf[qs][tc], lane = S[q0+16qs+l15][...]
    f32x4 sf[2][4];
#pragma unroll
    for (int tc = 0; tc < 4; ++tc) {
      const char* rowp = kbuf + (64 * tw + 16 * tc + l15) * 128;
      short8 a0 = *(const short8*)(rowp + ((16 * g) ^ sw));
      short8 a1 = *(const short8*)(rowp + ((64 + 16 * g) ^ sw));
      f32x4 z = (f32x4){0.f, 0.f, 0.f, 0.f};
      f32x4 t00 = __builtin_amdgcn_mfma_f32_16x16x32_bf16(a0, qf[0][0], z, 0, 0, 0);
      sf[0][tc] = __builtin_amdgcn_mfma_f32_16x16x32_bf16(a1, qf[0][1], t00, 0, 0, 0);
      f32x4 t10 = __builtin_amdgcn_mfma_f32_16x16x32_bf16(a0, qf[1][0], z, 0, 0, 0);
      sf[1][tc] = __builtin_amdgcn_mfma_f32_16x16x32_bf16(a1, qf[1][1], t10, 0, 0, 0);
    }

    // per q-subtile: mask+exp+pack (16 rows x 64t, proven swizzled layout),
    // read P frags; pbuf region reused qs-sequentially (wave-private)
    char* pbr = pb + l15 * 128;
    short8 p0[2], p1[2];
#pragma unroll
    for (int qs = 0; qs < 2; ++qs) {
      const uint2 mwq = qs ? mw1 : mw0;
#pragma unroll
      for (int tc = 0; tc < 4; ++tc) {
        unsigned word = (tc < 2) ? mwq.x : mwq.y;
        unsigned nib = (word >> (16 * (tc & 1) + 4 * g)) & 15u;
        float s0 = (nib & 1u) ? -1e9f : sf[qs][tc][0] * 0.125f;
        float s1 = (nib & 2u) ? -1e9f : sf[qs][tc][1] * 0.125f;
        float s2 = (nib & 4u) ? -1e9f : sf[qs][tc][2] * 0.125f;
        float s3 = (nib & 8u) ? -1e9f : sf[qs][tc][3] * 0.125f;
        float e = __expf(s0) + __expf(s1) + __expf(s2) + __expf(s3);
        if (qs) lp1 += e; else lp0 += e;
        int2 pk;
        pk.x = (int)f2bf(s0) | ((int)f2bf(s1) << 16);
        pk.y = (int)f2bf(s2) | ((int)f2bf(s3) << 16);
        *(int2*)(pbr + ((32 * tc + 8 * g) ^ sw)) = pk;
      }
      p0[qs] = *(const short8*)(pb + l15 * 128 + ((16 * g) ^ sw));
      p1[qs] = *(const short8*)(pb + l15 * 128 + ((64 + 16 * g) ^ sw));
    }

    // GEMM2: V frags hoisted across the two q-subtiles (own 64-t half)
#pragma unroll
    for (int dr = 0; dr < 4; ++dr) {
      const char* vr = vbuf + (16 * dr + l15) * 256 + 128 * tw;
      short8 v0 = *(const short8*)(vr + ((16 * g) ^ sw));
      short8 v1 = *(const short8*)(vr + ((64 + 16 * g) ^ sw));
      acc[dr][0] = __builtin_amdgcn_mfma_f32_16x16x32_bf16(
          v1, p1[0], __builtin_amdgcn_mfma_f32_16x16x32_bf16(v0, p0[0], acc[dr][0], 0, 0, 0), 0, 0, 0);
      acc[dr][1] = __builtin_amdgcn_mfma_f32_16x16x32_bf16(
          v1, p1[1], __builtin_amdgcn_mfma_f32_16x16x32_bf16(v0, p0[1], acc[dr][1], 0, 0, 0), 0, 0, 0);
    }

    mw0 = mwn0; mw1 = mwn1;
    __syncthreads();
    cur ^= 1;
  }

  // ---- cross-tw reduction: acc partials + row sums ----
  lp0 += __shfl_xor(lp0, 16); lp0 += __shfl_xor(lp0, 32);
  lp1 += __shfl_xor(lp1, 16); lp1 += __shfl_xor(lp1, 32);

  if (tw == 1) {
    if (lane < 16) {
      sums[qw * 32 + l15] = lp0;
      sums[qw * 32 + 16 + l15] = lp1;
    }
    char* ar = smem + 32768 + qw * 8192;
#pragma unroll
    for (int dr = 0; dr < 4; ++dr)
#pragma unroll
      for (int qs = 0; qs < 2; ++qs)
        *(f32x4*)(ar + (16 * qs + l15) * 256 + (((16 * dr + 4 * g) * 4) ^ ((l15 & 7) << 4))) = acc[dr][qs];
  }
  __syncthreads();
  if (tw == 0) {
    const char* ar = smem + 32768 + qw * 8192;
#pragma unroll
    for (int dr = 0; dr < 4; ++dr)
#pragma unroll
      for (int qs = 0; qs < 2; ++qs)
        acc[dr][qs] += *(const f32x4*)(ar + (16 * qs + l15) * 256 + (((16 * dr + 4 * g) * 4) ^ ((l15 & 7) << 4)));
    float tot0 = lp0 + sums[qw * 32 + l15];
    float tot1 = lp1 + sums[qw * 32 + 16 + l15];
    float i0 = 1.0f / tot0;
    float i1 = 1.0f / tot1;
    if (lane < 16) {
      invl[qw * 32 + l15] = i0;
      invl[qw * 32 + 16 + l15] = i1;
    }
    // write results: acc^T C-layout -> out[bh][q][d], float4 along d
#pragma unroll
    for (int dr = 0; dr < 4; ++dr) {
      float4 o0, o1;
      o0.x = acc[dr][0][0]; o0.y = acc[dr][0][1]; o0.z = acc[dr][0][2]; o0.w = acc[dr][0][3];
      o1.x = acc[dr][1][0]; o1.y = acc[dr][1][1]; o1.z = acc[dr][1][2]; o1.w = acc[dr][1][3];
      *(float4*)(out + ((size_t)bh * S_LEN + q0 + l15) * DH + 16 * dr + 4 * g) = o0;
      *(float4*)(out + ((size_t)bh * S_LEN + q0 + 16 + l15) * DH + 16 * dr + 4 * g) = o1;
    }
  }
  __syncthreads();

  // ------- PASS B: non-swapped MFMA, own 64-t half, row-major stores -------
  float* att = out + (size_t)4194304 + (size_t)bh * S_LEN * S_LEN;
  float invq0[4], invq1[4];
#pragma unroll
  for (int r = 0; r < 4; ++r) {
    invq0[r] = invl[qw * 32 + 4 * g + r];
    invq1[r] = invl[qw * 32 + 16 + 4 * g + r];
  }
  float* attq0 = att + (size_t)(q0 + 4 * g) * S_LEN + l15;
  float* attq1 = att + (size_t)(q0 + 16 + 4 * g) * S_LEN + l15;

  stageK(0, 0);
  uint2 mv0[4], mv1[4];
#pragma unroll
  for (int r = 0; r < 4; ++r) {
    mv0[r] = *(const uint2*)(mb_b + (size_t)(q0 + 4 * g + r) * 64 + 2 * tw);
    mv1[r] = *(const uint2*)(mb_b + (size_t)(q0 + 16 + 4 * g + r) * 64 + 2 * tw);
  }
  __syncthreads();
  cur = 0;

  for (int t0 = 0; t0 < S_LEN; t0 += 128) {
    uint2 nv0[4], nv1[4];
    if (t0 + 128 < S_LEN) {
      stageK(cur ^ 1, t0 + 128);
#pragma unroll
      for (int r = 0; r < 4; ++r) {
        nv0[r] = *(const uint2*)(mb_b + (size_t)(q0 + 4 * g + r) * 64 + (t0 + 128) / 32 + 2 * tw);
        nv1[r] = *(const uint2*)(mb_b + (size_t)(q0 + 16 + 4 * g + r) * 64 + (t0 + 128) / 32 + 2 * tw);
      }
    }
    const char* kbuf = smem + cur * 16384;

#pragma unroll
    for (int tc = 0; tc < 4; ++tc) {
      const char* rowp = kbuf + (64 * tw + 16 * tc + l15) * 128;
      short8 b0 = *(const short8*)(rowp + ((16 * g) ^ sw));
      short8 b1 = *(const short8*)(rowp + ((64 + 16 * g) ^ sw));
      f32x4 z = (f32x4){0.f, 0.f, 0.f, 0.f};
      // non-swapped: C[lane,reg r] = S[q0+16qs+4g+r][t0+64tw+16tc+l15]
      f32x4 t0f = __builtin_amdgcn_mfma_f32_16x16x32_bf16(qf[0][0], b0, z, 0, 0, 0);
      f32x4 s0f = __builtin_amdgcn_mfma_f32_16x16x32_bf16(qf[0][1], b1, t0f, 0, 0, 0);
      f32x4 t1f = __builtin_amdgcn_mfma_f32_16x16x32_bf16(qf[1][0], b0, z, 0, 0, 0);
      f32x4 s1f = __builtin_amdgcn_mfma_f32_16x16x32_bf16(qf[1][1], b1, t1f, 0, 0, 0);
      const int off = t0 + 64 * tw + 16 * tc;
      const int sh = 16 * (tc & 1) + l15;
#pragma unroll
      for (int r = 0; r < 4; ++r) {
        unsigned w0 = (tc < 2) ? mv0[r].x : mv0[r].y;
        float sa = ((w0 >> sh) & 1u) ? -1e9f : s0f[r] * 0.125f;
        attq0[(size_t)r * S_LEN + off] = __expf(sa) * invq0[r];
        unsigned w1 = (tc < 2) ? mv1[r].x : mv1[r].y;
        float sb = ((w1 >> sh) & 1u) ? -1e9f : s1f[r] * 0.125f;
        attq1[(size_t)r * S_LEN + off] = __expf(sb) * invq1[r];
      }
    }

#pragma unroll
    for (int r = 0; r < 4; ++r) { mv0[r] = nv0[r]; mv1[r] = nv1[r]; }
    __syncthreads();
    cur ^= 1;
  }
}

extern "C" void kernel_launch(void* const* d_in, const int* in_sizes, int n_in,
                              void* d_out, int out_size, void* d_ws, size_t ws_size,
                              hipStream_t stream) {
  (void)in_sizes; (void)n_in; (void)out_size; (void)ws_size;
  const float* q = (const float*)d_in[0];
  const float* k = (const float*)d_in[1];
  const float* v = (const float*)d_in[2];
  const unsigned char* mask = (const unsigned char*)d_in[3];
  float* out = (float*)d_out;

  char* ws = (char*)d_ws;
  int* flag = (int*)ws;
  char* kbf = ws + 256;                           // 8 MiB bf16 K
  char* vtbf = ws + 256 + 8 * 1024 * 1024;        // 8 MiB bf16 V^T
  unsigned* bits = (unsigned*)(ws + 256 + 16 * 1024 * 1024);  // 1 MiB bitmask

  detect_stride_k<<<1, 256, 0, stream>>>(mask, flag);
  prep_kernel<<<7168, 256, 0, stream>>>(k, v, mask, flag, kbf, vtbf, bits);
  attn_fused<<<512, 512, 0, stream>>>(q, bits, kbf, vtbf, out);
}

// Round 18
// 201.560 us; speedup vs baseline: 1.3397x; 1.3397x over previous
//
#include <hip/hip_runtime.h>

typedef __attribute__((ext_vector_type(8))) short short8;
typedef __attribute__((ext_vector_type(4))) float f32x4;

#define S_LEN 2048
#define DH 64

__device__ __forceinline__ unsigned short f2bf(float x) {
  unsigned u = __builtin_bit_cast(unsigned, x);
  u += 0x7fffu + ((u >> 16) & 1u);
  return (unsigned short)(u >> 16);
}

// ---- merged prep: conv K->bf16 | transpose V->bf16 | pack mask bits ----
// (mask dtype detected in-block: scan first 4 KB for nonzero off-word bytes)
__global__ void prep_kernel(const float* __restrict__ k,
                            const float* __restrict__ v,
                            const unsigned char* __restrict__ m,
                            char* __restrict__ kbf,
                            char* __restrict__ vtbf,
                            unsigned* __restrict__ bits) {
  int bid = blockIdx.x;
  if (bid < 2048) {
    int idx = bid * 256 + threadIdx.x;
    const float4* s = (const float4*)k + (size_t)idx * 2;
    float4 a = s[0], b = s[1];
    int4 o;
    o.x = (int)f2bf(a.x) | ((int)f2bf(a.y) << 16);
    o.y = (int)f2bf(a.z) | ((int)f2bf(a.w) << 16);
    o.z = (int)f2bf(b.x) | ((int)f2bf(b.y) << 16);
    o.w = (int)f2bf(b.z) | ((int)f2bf(b.w) << 16);
    ((int4*)kbf)[idx] = o;
  } else if (bid < 6144) {
    int gt = (bid - 2048) * 256 + threadIdx.x;
    int wid = gt >> 6;
    int lane = gt & 63;
    int bh = wid >> 9;
    int rem = wid & 511;
    int d0 = (rem >> 5) * 4;
    int t = (rem & 31) * 64 + lane;
    float4 val = *(const float4*)(v + ((size_t)bh * S_LEN + t) * DH + d0);
    unsigned short* o = (unsigned short*)vtbf;
    size_t base = ((size_t)bh * DH + d0) * S_LEN + t;
    o[base]             = f2bf(val.x);
    o[base + S_LEN]     = f2bf(val.y);
    o[base + 2 * S_LEN] = f2bf(val.z);
    o[base + 3 * S_LEN] = f2bf(val.w);
  } else {
    // in-block stride detect: any nonzero byte at offset i%4!=0 -> uint8 mask
    __shared__ int anyf;
    if (threadIdx.x == 0) anyf = 0;
    __syncthreads();
    {
      int acc = 0;
      const uint4* p4 = (const uint4*)m;
#pragma unroll
      for (int it = 0; it < 1; ++it) {
        uint4 vv = p4[threadIdx.x];          // 4 KB scanned by 256 threads
        acc |= (vv.x & 0xffffff00u) | (vv.y & 0xffffff00u) |
               (vv.z & 0xffffff00u) | (vv.w & 0xffffff00u);
      }
      if (acc) atomicOr(&anyf, 1);
    }
    __syncthreads();
    const bool is_u8 = (anyf != 0);

    int idx = (bid - 6144) * 256 + threadIdx.x;
    unsigned wword = 0;
    if (is_u8) {
      const uint4* p = (const uint4*)(m + (size_t)idx * 32);
      uint4 a = p[0], bq = p[1];
      unsigned arr[8] = {a.x, a.y, a.z, a.w, bq.x, bq.y, bq.z, bq.w};
#pragma unroll
      for (int d = 0; d < 8; ++d)
#pragma unroll
        for (int j = 0; j < 4; ++j)
          wword |= (((arr[d] >> (8 * j)) & 255u) != 0u ? 1u : 0u) << (d * 4 + j);
    } else {
      const uint4* p = (const uint4*)m + (size_t)idx * 8;
#pragma unroll
      for (int d = 0; d < 8; ++d) {
        uint4 vv = p[d];
        wword |= (vv.x ? 1u : 0u) << (d * 4);
        wword |= (vv.y ? 1u : 0u) << (d * 4 + 1);
        wword |= (vv.z ? 1u : 0u) << (d * 4 + 2);
        wword |= (vv.w ? 1u : 0u) << (d * 4 + 3);
      }
    }
    bits[idx] = wword;
  }
}

// ======= FUSED (R16 champion): pass A staged dbuf (swapped MFMA); pass B
// staged dbuf, NON-swapped MFMA -> quad-coalesced row-major stores;
// + pass-B mask prefetch. 512 blocks x 8 waves (16 q-rows each). ============
__global__ __launch_bounds__(512, 4)
void attn_fused(const float* __restrict__ qsrc,
                const unsigned* __restrict__ mbits,
                const char* __restrict__ kbf,
                const char* __restrict__ vtbf,
                float* __restrict__ out) {
  // 80 KiB: kbuf[2][16K] | vbuf[2][16K] | pbuf[16K]
  __shared__ __align__(16) char smem[81920];

  const int tid = threadIdx.x;
  const int lane = tid & 63;
  const int w = tid >> 6;              // 0..7
  const int l15 = lane & 15;
  const int g = lane >> 4;
  const int sw = (l15 & 7) << 4;

  // XCD-aware swizzle: 512 blocks -> 4 consecutive bh per XCD
  int raw = blockIdx.x;
  int swz = (raw & 7) * 64 + (raw >> 3);
  const int bh = swz >> 4;
  const int qblk = swz & 15;
  const int b = bh >> 4;
  const int q0 = qblk * 128 + w * 16;  // this wave's 16 q-rows

  const char* ksrc_bh = kbf + (size_t)bh * (S_LEN * DH * 2);
  const char* vsrc_bh = vtbf + (size_t)bh * (DH * S_LEN * 2);
  char* pb = smem + 65536 + w * 2048;  // 16 rows x 128 B, wave-private

  // this lane's q-row bitmask pointer: 64 words per row
  const unsigned* mrow = mbits + (size_t)b * (S_LEN * (S_LEN / 32)) +
                         (size_t)(q0 + l15) * (S_LEN / 32);

  auto stageK = [&](int buf, int t0) {
    char* dst = smem + buf * 16384;
#pragma unroll
    for (int it = 0; it < 2; ++it) {
      int o = (w * 2 + it) * 1024 + lane * 16;
      int r = o >> 7;
      int inner = o & 127;
      const char* gp = ksrc_bh + (size_t)t0 * 128 + r * 128 + (inner ^ ((r & 7) << 4));
      __builtin_amdgcn_global_load_lds((const unsigned*)gp,
                                       (unsigned*)(dst + (w * 2 + it) * 1024), 16, 0, 0);
    }
  };
  auto stageV = [&](int buf, int t0) {
    char* dst = smem + 32768 + buf * 16384;
#pragma unroll
    for (int it = 0; it < 2; ++it) {
      int o = (w * 2 + it) * 1024 + lane * 16;
      int r = o >> 8;
      int inner = o & 255;
      const char* gp = vsrc_bh + (size_t)t0 * 2 + (size_t)r * (S_LEN * 2) +
                       (inner ^ ((r & 7) << 4));
      __builtin_amdgcn_global_load_lds((const unsigned*)gp,
                                       (unsigned*)(dst + (w * 2 + it) * 1024), 16, 0, 0);
    }
  };

  // Q fragments: lane holds Q[q0+l15][32kc+8g+j]
  short8 qf[2];
#pragma unroll
  for (int kc = 0; kc < 2; ++kc) {
    const float* qp = qsrc + ((size_t)bh * S_LEN + q0 + l15) * DH + 32 * kc + 8 * g;
    float4 x = *(const float4*)qp;
    float4 y = *(const float4*)(qp + 4);
    short8 f;
    f[0] = (short)f2bf(x.x); f[1] = (short)f2bf(x.y);
    f[2] = (short)f2bf(x.z); f[3] = (short)f2bf(x.w);
    f[4] = (short)f2bf(y.x); f[5] = (short)f2bf(y.y);
    f[6] = (short)f2bf(y.z); f[7] = (short)f2bf(y.w);
    qf[kc] = f;
  }

  f32x4 acc[4];
#pragma unroll
  for (int i = 0; i < 4; ++i) acc[i] = (f32x4){0.f, 0.f, 0.f, 0.f};
  float lp = 0.f;

  // ---------------- PASS A (pipelined, staged; swapped MFMA) ----------------
  stageK(0, 0);
  stageV(0, 0);
  uint4 mw = *(const uint4*)mrow;      // tile-0 mask bits (128 t = 16 B)
  __syncthreads();
  int cur = 0;

  for (int t0 = 0; t0 < S_LEN; t0 += 128) {
    uint4 mw_n;
    if (t0 + 128 < S_LEN) {            // async prefetch of next tile
      stageK(cur ^ 1, t0 + 128);
      stageV(cur ^ 1, t0 + 128);
      mw_n = *(const uint4*)(mrow + (t0 + 128) / 32);
    }
    const char* kbuf = smem + cur * 16384;
    const char* vbuf = smem + 32768 + cur * 16384;

    // GEMM1 (swapped): lane holds S[q=q0+l15][t=t0+16tc+4g+r]
    f32x4 sf[8];
#pragma unroll
    for (int tc = 0; tc < 8; ++tc) {
      const char* rowp = kbuf + (16 * tc + l15) * 128;
      short8 a0 = *(const short8*)(rowp + ((16 * g) ^ sw));
      short8 a1 = *(const short8*)(rowp + ((64 + 16 * g) ^ sw));
      f32x4 z = (f32x4){0.f, 0.f, 0.f, 0.f};
      f32x4 t00 = __builtin_amdgcn_mfma_f32_16x16x32_bf16(a0, qf[0], z, 0, 0, 0);
      sf[tc] = __builtin_amdgcn_mfma_f32_16x16x32_bf16(a1, qf[1], t00, 0, 0, 0);
    }

    // two 64-t halves: mask+exp+pack P -> GEMM2 (wave-private pbuf, no barrier)
    const unsigned mwa[4] = {mw.x, mw.y, mw.z, mw.w};
#pragma unroll
    for (int h = 0; h < 2; ++h) {
      char* pbr = pb + l15 * 128;
#pragma unroll
      for (int tq = 0; tq < 4; ++tq) {
        const int tc = 4 * h + tq;
        unsigned nib = (mwa[tc >> 1] >> (16 * (tc & 1) + 4 * g)) & 15u;
        float s0 = (nib & 1u) ? -1e9f : sf[tc][0] * 0.125f;
        float s1 = (nib & 2u) ? -1e9f : sf[tc][1] * 0.125f;
        float s2 = (nib & 4u) ? -1e9f : sf[tc][2] * 0.125f;
        float s3 = (nib & 8u) ? -1e9f : sf[tc][3] * 0.125f;
        lp += __expf(s0) + __expf(s1) + __expf(s2) + __expf(s3);
        int2 pk;
        pk.x = (int)f2bf(s0) | ((int)f2bf(s1) << 16);
        pk.y = (int)f2bf(s2) | ((int)f2bf(s3) << 16);
        *(int2*)(pbr + ((32 * tq + 8 * g) ^ sw)) = pk;
      }
      short8 p0 = *(const short8*)(pb + l15 * 128 + ((16 * g) ^ sw));
      short8 p1 = *(const short8*)(pb + l15 * 128 + ((64 + 16 * g) ^ sw));
#pragma unroll
      for (int dr = 0; dr < 4; ++dr) {
        const char* vr = vbuf + (16 * dr + l15) * 256;
        short8 v0 = *(const short8*)(vr + ((h * 128 + 16 * g) ^ sw));
        short8 v1 = *(const short8*)(vr + ((h * 128 + 64 + 16 * g) ^ sw));
        acc[dr] = __builtin_amdgcn_mfma_f32_16x16x32_bf16(v0, p0, acc[dr], 0, 0, 0);
        acc[dr] = __builtin_amdgcn_mfma_f32_16x16x32_bf16(v1, p1, acc[dr], 0, 0, 0);
      }
    }

    mw = mw_n;
    __syncthreads();   // drains prefetch (covered by compute) + guards buffers
    cur ^= 1;
  }

  // row sums (row q0+l15 lives on lanes {l15, +16, +32, +48})
  float l = lp;
  l += __shfl_xor(l, 16);
  l += __shfl_xor(l, 32);
  const float inv = 1.0f / l;

  // write results: acc^T C-layout -> out[bh][q][d], float4 along d
#pragma unroll
  for (int dr = 0; dr < 4; ++dr) {
    float4 o;
    o.x = acc[dr][0]; o.y = acc[dr][1];
    o.z = acc[dr][2]; o.w = acc[dr][3];
    *(float4*)(out + ((size_t)bh * S_LEN + q0 + l15) * DH + 16 * dr + 4 * g) = o;
  }

  // ------- PASS B: non-swapped MFMA -> quad-coalesced row-major stores ------
  float* att = out + (size_t)4194304 + (size_t)bh * S_LEN * S_LEN;

  // inv for the 4 q-rows (q0+4g+r) this lane writes in the C row layout
  float invr[4];
#pragma unroll
  for (int r = 0; r < 4; ++r) invr[r] = __shfl(inv, 4 * g + r, 64);

  const unsigned* mrowB = mbits + (size_t)b * (S_LEN * (S_LEN / 32)) +
                          (size_t)(q0 + 4 * g) * (S_LEN / 32);

  stageK(0, 0);
  uint4 mv[4];
#pragma unroll
  for (int r = 0; r < 4; ++r) mv[r] = *(const uint4*)(mrowB + r * 64);
  __syncthreads();
  cur = 0;

  for (int t0 = 0; t0 < S_LEN; t0 += 128) {
    uint4 nv[4];
    if (t0 + 128 < S_LEN) {
      stageK(cur ^ 1, t0 + 128);
#pragma unroll
      for (int r = 0; r < 4; ++r)
        nv[r] = *(const uint4*)(mrowB + r * 64 + (t0 + 128) / 32);
    }
    const char* kbuf = smem + cur * 16384;

    float* attT = att + (size_t)(q0 + 4 * g) * S_LEN + t0 + l15;

#pragma unroll
    for (int tc = 0; tc < 8; ++tc) {
      const char* rowp = kbuf + (16 * tc + l15) * 128;
      short8 b0 = *(const short8*)(rowp + ((16 * g) ^ sw));
      short8 b1 = *(const short8*)(rowp + ((64 + 16 * g) ^ sw));
      f32x4 z = (f32x4){0.f, 0.f, 0.f, 0.f};
      // non-swapped: C[lane,reg r] = S[q0+4g+r][t0+16tc+l15]
      f32x4 t0f = __builtin_amdgcn_mfma_f32_16x16x32_bf16(qf[0], b0, z, 0, 0, 0);
      f32x4 sff = __builtin_amdgcn_mfma_f32_16x16x32_bf16(qf[1], b1, t0f, 0, 0, 0);
      const int bitsh = 16 * (tc & 1) + l15;
#pragma unroll
      for (int r = 0; r < 4; ++r) {
        unsigned word = (tc >> 1) == 0 ? mv[r].x : (tc >> 1) == 1 ? mv[r].y
                      : (tc >> 1) == 2 ? mv[r].z : mv[r].w;
        float s = ((word >> bitsh) & 1u) ? -1e9f : sff[r] * 0.125f;
        attT[(size_t)r * S_LEN + 16 * tc] = __expf(s) * invr[r];
      }
    }

#pragma unroll
    for (int r = 0; r < 4; ++r) mv[r] = nv[r];
    __syncthreads();
    cur ^= 1;
  }
}

extern "C" void kernel_launch(void* const* d_in, const int* in_sizes, int n_in,
                              void* d_out, int out_size, void* d_ws, size_t ws_size,
                              hipStream_t stream) {
  (void)in_sizes; (void)n_in; (void)out_size; (void)ws_size;
  const float* q = (const float*)d_in[0];
  const float* k = (const float*)d_in[1];
  const float* v = (const float*)d_in[2];
  const unsigned char* mask = (const unsigned char*)d_in[3];
  float* out = (float*)d_out;

  char* ws = (char*)d_ws;
  char* kbf = ws + 256;                           // 8 MiB bf16 K
  char* vtbf = ws + 256 + 8 * 1024 * 1024;        // 8 MiB bf16 V^T
  unsigned* bits = (unsigned*)(ws + 256 + 16 * 1024 * 1024);  // 1 MiB bitmask

  prep_kernel<<<7168, 256, 0, stream>>>(k, v, mask, kbf, vtbf, bits);
  attn_fused<<<512, 512, 0, stream>>>(q, bits, kbf, vtbf, out);
}

// Round 20
// 200.091 us; speedup vs baseline: 1.3495x; 1.0073x over previous
//
#include <hip/hip_runtime.h>

typedef __attribute__((ext_vector_type(8))) short short8;
typedef __attribute__((ext_vector_type(4))) float f32x4;

#define S_LEN 2048
#define DH 64

__device__ __forceinline__ unsigned short f2bf(float x) {
  unsigned u = __builtin_bit_cast(unsigned, x);
  u += 0x7fffu + ((u >> 16) & 1u);
  return (unsigned short)(u >> 16);
}

// ---- merged prep: conv K->bf16 | transpose V->bf16 | pack mask bits ----
// (mask dtype detected in-block: scan first 4 KB for nonzero off-word bytes)
__global__ void prep_kernel(const float* __restrict__ k,
                            const float* __restrict__ v,
                            const unsigned char* __restrict__ m,
                            char* __restrict__ kbf,
                            char* __restrict__ vtbf,
                            unsigned* __restrict__ bits) {
  int bid = blockIdx.x;
  if (bid < 2048) {
    int idx = bid * 256 + threadIdx.x;
    const float4* s = (const float4*)k + (size_t)idx * 2;
    float4 a = s[0], b = s[1];
    int4 o;
    o.x = (int)f2bf(a.x) | ((int)f2bf(a.y) << 16);
    o.y = (int)f2bf(a.z) | ((int)f2bf(a.w) << 16);
    o.z = (int)f2bf(b.x) | ((int)f2bf(b.y) << 16);
    o.w = (int)f2bf(b.z) | ((int)f2bf(b.w) << 16);
    ((int4*)kbf)[idx] = o;
  } else if (bid < 6144) {
    int gt = (bid - 2048) * 256 + threadIdx.x;
    int wid = gt >> 6;
    int lane = gt & 63;
    int bh = wid >> 9;
    int rem = wid & 511;
    int d0 = (rem >> 5) * 4;
    int t = (rem & 31) * 64 + lane;
    float4 val = *(const float4*)(v + ((size_t)bh * S_LEN + t) * DH + d0);
    unsigned short* o = (unsigned short*)vtbf;
    size_t base = ((size_t)bh * DH + d0) * S_LEN + t;
    o[base]             = f2bf(val.x);
    o[base + S_LEN]     = f2bf(val.y);
    o[base + 2 * S_LEN] = f2bf(val.z);
    o[base + 3 * S_LEN] = f2bf(val.w);
  } else {
    // in-block stride detect: any nonzero byte at offset i%4!=0 -> uint8 mask
    __shared__ int anyf;
    if (threadIdx.x == 0) anyf = 0;
    __syncthreads();
    {
      int acc = 0;
      const uint4* p4 = (const uint4*)m;
#pragma unroll
      for (int it = 0; it < 1; ++it) {
        uint4 vv = p4[threadIdx.x];          // 4 KB scanned by 256 threads
        acc |= (vv.x & 0xffffff00u) | (vv.y & 0xffffff00u) |
               (vv.z & 0xffffff00u) | (vv.w & 0xffffff00u);
      }
      if (acc) atomicOr(&anyf, 1);
    }
    __syncthreads();
    const bool is_u8 = (anyf != 0);

    int idx = (bid - 6144) * 256 + threadIdx.x;
    unsigned wword = 0;
    if (is_u8) {
      const uint4* p = (const uint4*)(m + (size_t)idx * 32);
      uint4 a = p[0], bq = p[1];
      unsigned arr[8] = {a.x, a.y, a.z, a.w, bq.x, bq.y, bq.z, bq.w};
#pragma unroll
      for (int d = 0; d < 8; ++d)
#pragma unroll
        for (int j = 0; j < 4; ++j)
          wword |= (((arr[d] >> (8 * j)) & 255u) != 0u ? 1u : 0u) << (d * 4 + j);
    } else {
      const uint4* p = (const uint4*)m + (size_t)idx * 8;
#pragma unroll
      for (int d = 0; d < 8; ++d) {
        uint4 vv = p[d];
        wword |= (vv.x ? 1u : 0u) << (d * 4);
        wword |= (vv.y ? 1u : 0u) << (d * 4 + 1);
        wword |= (vv.z ? 1u : 0u) << (d * 4 + 2);
        wword |= (vv.w ? 1u : 0u) << (d * 4 + 3);
      }
    }
    bits[idx] = wword;
  }
}

// ======= FUSED (champion): pass A staged dbuf (swapped MFMA); pass B
// staged dbuf, NON-swapped MFMA -> quad-coalesced row-major stores;
// + pass-B mask prefetch. 512 blocks x 8 waves (16 q-rows each). ============
__global__ __launch_bounds__(512, 4)
void attn_fused(const float* __restrict__ qsrc,
                const unsigned* __restrict__ mbits,
                const char* __restrict__ kbf,
                const char* __restrict__ vtbf,
                float* __restrict__ out) {
  // 80 KiB: kbuf[2][16K] | vbuf[2][16K] | pbuf[16K]
  __shared__ __align__(16) char smem[81920];

  const int tid = threadIdx.x;
  const int lane = tid & 63;
  const int w = tid >> 6;              // 0..7
  const int l15 = lane & 15;
  const int g = lane >> 4;
  const int sw = (l15 & 7) << 4;

  // XCD-aware swizzle: 512 blocks -> 4 consecutive bh per XCD
  int raw = blockIdx.x;
  int swz = (raw & 7) * 64 + (raw >> 3);
  const int bh = swz >> 4;
  const int qblk = swz & 15;
  const int b = bh >> 4;
  const int q0 = qblk * 128 + w * 16;  // this wave's 16 q-rows

  const char* ksrc_bh = kbf + (size_t)bh * (S_LEN * DH * 2);
  const char* vsrc_bh = vtbf + (size_t)bh * (DH * S_LEN * 2);
  char* pb = smem + 65536 + w * 2048;  // 16 rows x 128 B, wave-private

  // this lane's q-row bitmask pointer: 64 words per row
  const unsigned* mrow = mbits + (size_t)b * (S_LEN * (S_LEN / 32)) +
                         (size_t)(q0 + l15) * (S_LEN / 32);

  auto stageK = [&](int buf, int t0) {
    char* dst = smem + buf * 16384;
#pragma unroll
    for (int it = 0; it < 2; ++it) {
      int o = (w * 2 + it) * 1024 + lane * 16;
      int r = o >> 7;
      int inner = o & 127;
      const char* gp = ksrc_bh + (size_t)t0 * 128 + r * 128 + (inner ^ ((r & 7) << 4));
      __builtin_amdgcn_global_load_lds((const unsigned*)gp,
                                       (unsigned*)(dst + (w * 2 + it) * 1024), 16, 0, 0);
    }
  };
  auto stageV = [&](int buf, int t0) {
    char* dst = smem + 32768 + buf * 16384;
#pragma unroll
    for (int it = 0; it < 2; ++it) {
      int o = (w * 2 + it) * 1024 + lane * 16;
      int r = o >> 8;
      int inner = o & 255;
      const char* gp = vsrc_bh + (size_t)t0 * 2 + (size_t)r * (S_LEN * 2) +
                       (inner ^ ((r & 7) << 4));
      __builtin_amdgcn_global_load_lds((const unsigned*)gp,
                                       (unsigned*)(dst + (w * 2 + it) * 1024), 16, 0, 0);
    }
  };

  // Q fragments: lane holds Q[q0+l15][32kc+8g+j]
  short8 qf[2];
#pragma unroll
  for (int kc = 0; kc < 2; ++kc) {
    const float* qp = qsrc + ((size_t)bh * S_LEN + q0 + l15) * DH + 32 * kc + 8 * g;
    float4 x = *(const float4*)qp;
    float4 y = *(const float4*)(qp + 4);
    short8 f;
    f[0] = (short)f2bf(x.x); f[1] = (short)f2bf(x.y);
    f[2] = (short)f2bf(x.z); f[3] = (short)f2bf(x.w);
    f[4] = (short)f2bf(y.x); f[5] = (short)f2bf(y.y);
    f[6] = (short)f2bf(y.z); f[7] = (short)f2bf(y.w);
    qf[kc] = f;
  }

  f32x4 acc[4];
#pragma unroll
  for (int i = 0; i < 4; ++i) acc[i] = (f32x4){0.f, 0.f, 0.f, 0.f};
  float lp = 0.f;

  // ---------------- PASS A (pipelined, staged; swapped MFMA) ----------------
  stageK(0, 0);
  stageV(0, 0);
  uint4 mw = *(const uint4*)mrow;      // tile-0 mask bits (128 t = 16 B)
  __syncthreads();
  int cur = 0;

  for (int t0 = 0; t0 < S_LEN; t0 += 128) {
    uint4 mw_n;
    if (t0 + 128 < S_LEN) {            // async prefetch of next tile
      stageK(cur ^ 1, t0 + 128);
      stageV(cur ^ 1, t0 + 128);
      mw_n = *(const uint4*)(mrow + (t0 + 128) / 32);
    }
    const char* kbuf = smem + cur * 16384;
    const char* vbuf = smem + 32768 + cur * 16384;

    // GEMM1 (swapped): lane holds S[q=q0+l15][t=t0+16tc+4g+r]
    f32x4 sf[8];
#pragma unroll
    for (int tc = 0; tc < 8; ++tc) {
      const char* rowp = kbuf + (16 * tc + l15) * 128;
      short8 a0 = *(const short8*)(rowp + ((16 * g) ^ sw));
      short8 a1 = *(const short8*)(rowp + ((64 + 16 * g) ^ sw));
      f32x4 z = (f32x4){0.f, 0.f, 0.f, 0.f};
      f32x4 t00 = __builtin_amdgcn_mfma_f32_16x16x32_bf16(a0, qf[0], z, 0, 0, 0);
      sf[tc] = __builtin_amdgcn_mfma_f32_16x16x32_bf16(a1, qf[1], t00, 0, 0, 0);
    }

    // two 64-t halves: mask+exp+pack P -> GEMM2 (wave-private pbuf, no barrier)
    const unsigned mwa[4] = {mw.x, mw.y, mw.z, mw.w};
#pragma unroll
    for (int h = 0; h < 2; ++h) {
      char* pbr = pb + l15 * 128;
#pragma unroll
      for (int tq = 0; tq < 4; ++tq) {
        const int tc = 4 * h + tq;
        unsigned nib = (mwa[tc >> 1] >> (16 * (tc & 1) + 4 * g)) & 15u;
        float s0 = (nib & 1u) ? -1e9f : sf[tc][0] * 0.125f;
        float s1 = (nib & 2u) ? -1e9f : sf[tc][1] * 0.125f;
        float s2 = (nib & 4u) ? -1e9f : sf[tc][2] * 0.125f;
        float s3 = (nib & 8u) ? -1e9f : sf[tc][3] * 0.125f;
        lp += __expf(s0) + __expf(s1) + __expf(s2) + __expf(s3);
        int2 pk;
        pk.x = (int)f2bf(s0) | ((int)f2bf(s1) << 16);
        pk.y = (int)f2bf(s2) | ((int)f2bf(s3) << 16);
        *(int2*)(pbr + ((32 * tq + 8 * g) ^ sw)) = pk;
      }
      short8 p0 = *(const short8*)(pb + l15 * 128 + ((16 * g) ^ sw));
      short8 p1 = *(const short8*)(pb + l15 * 128 + ((64 + 16 * g) ^ sw));
#pragma unroll
      for (int dr = 0; dr < 4; ++dr) {
        const char* vr = vbuf + (16 * dr + l15) * 256;
        short8 v0 = *(const short8*)(vr + ((h * 128 + 16 * g) ^ sw));
        short8 v1 = *(const short8*)(vr + ((h * 128 + 64 + 16 * g) ^ sw));
        acc[dr] = __builtin_amdgcn_mfma_f32_16x16x32_bf16(v0, p0, acc[dr], 0, 0, 0);
        acc[dr] = __builtin_amdgcn_mfma_f32_16x16x32_bf16(v1, p1, acc[dr], 0, 0, 0);
      }
    }

    mw = mw_n;
    __syncthreads();   // drains prefetch (covered by compute) + guards buffers
    cur ^= 1;
  }

  // row sums (row q0+l15 lives on lanes {l15, +16, +32, +48})
  float l = lp;
  l += __shfl_xor(l, 16);
  l += __shfl_xor(l, 32);
  const float inv = 1.0f / l;

  // write results: acc^T C-layout -> out[bh][q][d], float4 along d
#pragma unroll
  for (int dr = 0; dr < 4; ++dr) {
    float4 o;
    o.x = acc[dr][0]; o.y = acc[dr][1];
    o.z = acc[dr][2]; o.w = acc[dr][3];
    *(float4*)(out + ((size_t)bh * S_LEN + q0 + l15) * DH + 16 * dr + 4 * g) = o;
  }

  // ------- PASS B: non-swapped MFMA -> quad-coalesced row-major stores ------
  float* att = out + (size_t)4194304 + (size_t)bh * S_LEN * S_LEN;

  // inv for the 4 q-rows (q0+4g+r) this lane writes in the C row layout
  float invr[4];
#pragma unroll
  for (int r = 0; r < 4; ++r) invr[r] = __shfl(inv, 4 * g + r, 64);

  const unsigned* mrowB = mbits + (size_t)b * (S_LEN * (S_LEN / 32)) +
                          (size_t)(q0 + 4 * g) * (S_LEN / 32);

  stageK(0, 0);
  uint4 mv[4];
#pragma unroll
  for (int r = 0; r < 4; ++r) mv[r] = *(const uint4*)(mrowB + r * 64);
  __syncthreads();
  cur = 0;

  for (int t0 = 0; t0 < S_LEN; t0 += 128) {
    uint4 nv[4];
    if (t0 + 128 < S_LEN) {
      stageK(cur ^ 1, t0 + 128);
#pragma unroll
      for (int r = 0; r < 4; ++r)
        nv[r] = *(const uint4*)(mrowB + r * 64 + (t0 + 128) / 32);
    }
    const char* kbuf = smem + cur * 16384;

    float* attT = att + (size_t)(q0 + 4 * g) * S_LEN + t0 + l15;

#pragma unroll
    for (int tc = 0; tc < 8; ++tc) {
      const char* rowp = kbuf + (16 * tc + l15) * 128;
      short8 b0 = *(const short8*)(rowp + ((16 * g) ^ sw));
      short8 b1 = *(const short8*)(rowp + ((64 + 16 * g) ^ sw));
      f32x4 z = (f32x4){0.f, 0.f, 0.f, 0.f};
      // non-swapped: C[lane,reg r] = S[q0+4g+r][t0+16tc+l15]
      f32x4 t0f = __builtin_amdgcn_mfma_f32_16x16x32_bf16(qf[0], b0, z, 0, 0, 0);
      f32x4 sff = __builtin_amdgcn_mfma_f32_16x16x32_bf16(qf[1], b1, t0f, 0, 0, 0);
      const int bitsh = 16 * (tc & 1) + l15;
#pragma unroll
      for (int r = 0; r < 4; ++r) {
        unsigned word = (tc >> 1) == 0 ? mv[r].x : (tc >> 1) == 1 ? mv[r].y
                      : (tc >> 1) == 2 ? mv[r].z : mv[r].w;
        float s = ((word >> bitsh) & 1u) ? -1e9f : sff[r] * 0.125f;
        attT[(size_t)r * S_LEN + 16 * tc] = __expf(s) * invr[r];
      }
    }

#pragma unroll
    for (int r = 0; r < 4; ++r) mv[r] = nv[r];
    __syncthreads();
    cur ^= 1;
  }
}

extern "C" void kernel_launch(void* const* d_in, const int* in_sizes, int n_in,
                              void* d_out, int out_size, void* d_ws, size_t ws_size,
                              hipStream_t stream) {
  (void)in_sizes; (void)n_in; (void)out_size; (void)ws_size;
  const float* q = (const float*)d_in[0];
  const float* k = (const float*)d_in[1];
  const float* v = (const float*)d_in[2];
  const unsigned char* mask = (const unsigned char*)d_in[3];
  float* out = (float*)d_out;

  char* ws = (char*)d_ws;
  char* kbf = ws + 256;                           // 8 MiB bf16 K
  char* vtbf = ws + 256 + 8 * 1024 * 1024;        // 8 MiB bf16 V^T
  unsigned* bits = (unsigned*)(ws + 256 + 16 * 1024 * 1024);  // 1 MiB bitmask

  prep_kernel<<<7168, 256, 0, stream>>>(k, v, mask, kbf, vtbf, bits);
  attn_fused<<<512, 512, 0, stream>>>(q, bits, kbf, vtbf, out);
}